// Round 1
// baseline (628.104 us; speedup 1.0000x reference)
//
#include <hip/hip_runtime.h>
#include <hip/hip_bf16.h>

#define B_ 256
#define S_ 1024
#define D_ 128
#define H_ 256

typedef short short8 __attribute__((ext_vector_type(8)));
typedef float f32x4 __attribute__((ext_vector_type(4)));

// bf16 round-to-nearest-even (same conversion used for staging AND the c-vector
// compensation term, so the systematic quantization error cancels exactly).
__device__ __forceinline__ unsigned short f2bf(float x) {
    union { float f; unsigned u; } v; v.f = x;
    unsigned r = v.u + 0x7FFFu + ((v.u >> 16) & 1u);
    return (unsigned short)(r >> 16);
}
__device__ __forceinline__ float bf2f(unsigned short h) {
    union { float f; unsigned u; } v; v.u = ((unsigned)h) << 16;
    return v.f;
}
// tanh(x) = 1 - 2/(1+e^{2x}); exp2/rcp are ~1ulp, saturates correctly at +/-inf
__device__ __forceinline__ float fast_tanh(float x) {
    float e = __builtin_amdgcn_exp2f(x * 2.885390081777927f); // 2*log2(e)
    float r = __builtin_amdgcn_rcpf(1.0f + e);
    return 1.0f - 2.0f * r;
}

__global__ __launch_bounds__(512, 2) void set_net_kernel(
    const float* __restrict__ x,
    const float* __restrict__ W0, const float* __restrict__ b0,
    const float* __restrict__ W1, const float* __restrict__ b1,
    const float* __restrict__ W2, const float* __restrict__ b2,
    float* __restrict__ out, unsigned short* __restrict__ ws)
{
    const int blk  = blockIdx.x;       // one block per set, 256 blocks = 256 CUs
    const int t    = threadIdx.x;      // 0..511 (8 waves)
    const int lane = t & 63;
    const int wave = t >> 6;
    const int l15  = lane & 15;
    const int quad = lane >> 4;
    const int m_half = wave >> 2;      // 0..1  -> 64-row half of the 128-row tile
    const int n_q    = wave & 3;       // 0..3  -> 64-col quarter of 256 cols

    // LDS: rows padded to 40 ushorts (80 B) -> frag/staging accesses are <=2-way
    // bank aliased (free on gfx950), and 16B-aligned for b128 ops.
    __shared__ unsigned short A_lds[128 * 40];   // 10.0 KB  [row][k] bf16
    __shared__ unsigned short Bl_lds[256 * 40];  // 20.0 KB  [n][k]   bf16
    __shared__ float mean_lds[256];
    __shared__ float c_lds[256];
    __shared__ float colsum[256];
    __shared__ float red4[4][128];

    unsigned short* yb = ws + (size_t)blk * (S_ * H_);   // 512 KB per block
    const float*    xb = x  + (size_t)blk * (S_ * D_);

    // ---- Phase 0: column mean of x (fp32) + write bf16(x) into ws cols 0..127
    {
        int col = t & 127, rg = t >> 7;
        float s = 0.f;
        for (int r = rg; r < S_; r += 4) {
            float v = xb[r * D_ + col];
            s += v;
            yb[r * H_ + col] = f2bf(v);   // row stride 256 so layer0 writes in-place
        }
        red4[rg][col] = s;
    }
    __syncthreads();
    if (t < 128)
        mean_lds[t] = (red4[0][t] + red4[1][t] + red4[2][t] + red4[3][t]) * (1.f / S_);

    for (int l = 0; l < 3; ++l) {
        const int K = (l == 0) ? D_ : H_;
        const float* W  = (l == 0) ? W0 : (l == 1) ? W1 : W2;
        const float* bb = (l == 0) ? b0 : (l == 1) ? b1 : b2;
        __syncthreads();
        // c[j] = b[j] + mean @ W_right[j,:] + mean @ (W_left - bf16(W_left))[j,:]
        if (t < H_) {
            float acc = bb[t];
            const float* wr = W + t * 2 * K;
            for (int k = 0; k < K; ++k) {
                float m  = mean_lds[k];
                float wl = wr[k];
                acc += wr[K + k] * m + (wl - bf2f(f2bf(wl))) * m;
            }
            c_lds[t]  = acc;
            colsum[t] = 0.f;
        }
        __syncthreads();

        for (int mt = 0; mt < S_ / 128; ++mt) {
            f32x4 acc[4][4];
            #pragma unroll
            for (int i = 0; i < 4; ++i)
                #pragma unroll
                for (int j = 0; j < 4; ++j)
                    acc[i][j] = (f32x4){0.f, 0.f, 0.f, 0.f};

            for (int kc = 0; kc < K / 32; ++kc) {
                // stage A: 128 rows x 32 k bf16 from ws (each thread one 16B load)
                {
                    int row = t >> 2, q = t & 3;
                    const uint4* src =
                        (const uint4*)(yb + (size_t)(mt * 128 + row) * H_ + kc * 32 + q * 8);
                    *(uint4*)(&A_lds[row * 40 + q * 8]) = *src;
                }
                // stage B: 256 n x 32 k, fp32 W -> bf16 (W is L2-hot, shared by all blocks)
                {
                    int n = t >> 1, h = t & 1;
                    const float* wsrc = W + (size_t)n * 2 * K + kc * 32 + h * 16;
                    unsigned short tmp[16];
                    #pragma unroll
                    for (int i = 0; i < 16; ++i) tmp[i] = f2bf(wsrc[i]);
                    *(uint4*)(&Bl_lds[n * 40 + h * 16])     = *(const uint4*)(&tmp[0]);
                    *(uint4*)(&Bl_lds[n * 40 + h * 16 + 8]) = *(const uint4*)(&tmp[8]);
                }
                __syncthreads();

                short8 a[4], bfr[4];
                #pragma unroll
                for (int ms = 0; ms < 4; ++ms) {
                    int r = m_half * 64 + ms * 16 + l15;
                    a[ms] = *(const short8*)(&A_lds[r * 40 + quad * 8]);
                }
                #pragma unroll
                for (int ns = 0; ns < 4; ++ns) {
                    int n = n_q * 64 + ns * 16 + l15;
                    bfr[ns] = *(const short8*)(&Bl_lds[n * 40 + quad * 8]);
                }
                #pragma unroll
                for (int ms = 0; ms < 4; ++ms)
                    #pragma unroll
                    for (int ns = 0; ns < 4; ++ns)
                        acc[ms][ns] = __builtin_amdgcn_mfma_f32_16x16x32_bf16(
                            a[ms], bfr[ns], acc[ms][ns], 0, 0, 0);
                __syncthreads();
            }

            // epilogue: z = acc + c; y = tanh(z); colsum += y; store bf16(y)
            // C/D layout: col = lane&15, row = quad*4 + reg   [measured m89/m91]
            #pragma unroll
            for (int ns = 0; ns < 4; ++ns) {
                int col = n_q * 64 + ns * 16 + l15;
                float cv = c_lds[col];
                float sn = 0.f;
                #pragma unroll
                for (int ms = 0; ms < 4; ++ms) {
                    int rowbase = mt * 128 + m_half * 64 + ms * 16 + quad * 4;
                    #pragma unroll
                    for (int r = 0; r < 4; ++r) {
                        float z  = acc[ms][ns][r] + cv;
                        float th = fast_tanh(z);
                        sn += th;
                        if (l < 2)
                            yb[(size_t)(rowbase + r) * H_ + col] = f2bf(th);
                    }
                }
                // lanes {L, L^16, L^32, L^48} share a column -> butterfly then 1 atomic
                sn += __shfl_xor(sn, 16);
                sn += __shfl_xor(sn, 32);
                if (quad == 0) atomicAdd(&colsum[col], sn);
            }
        }
        __syncthreads();
        if (t < H_) mean_lds[t] = colsum[t] * (1.f / S_);
    }
    __syncthreads();
    if (t < H_) out[(size_t)blk * H_ + t] = colsum[t] * (1.f / S_);
}

extern "C" void kernel_launch(void* const* d_in, const int* in_sizes, int n_in,
                              void* d_out, int out_size, void* d_ws, size_t ws_size,
                              hipStream_t stream) {
    (void)in_sizes; (void)n_in; (void)out_size; (void)ws_size;
    const float* x  = (const float*)d_in[0];
    const float* W0 = (const float*)d_in[1];
    const float* b0 = (const float*)d_in[2];
    const float* W1 = (const float*)d_in[3];
    const float* b1 = (const float*)d_in[4];
    const float* W2 = (const float*)d_in[5];
    const float* b2 = (const float*)d_in[6];
    float* out = (float*)d_out;
    unsigned short* ws = (unsigned short*)d_ws;

    set_net_kernel<<<dim3(B_), dim3(512), 0, stream>>>(
        x, W0, b0, W1, b1, W2, b2, out, ws);
}